// Round 2
// baseline (448.172 us; speedup 1.0000x reference)
//
#include <hip/hip_runtime.h>

// Complex FIR, taps=11, SAME padding, stride 1 (cross-correlation, no flip).
// X: (128, 262144, 2) fp32 interleaved -> float2. phi: (11,2,1) fp32.
// out[b,n] = sum_k X[b, n-5+k] * phi[k]  (complex mul, zero-pad at row edges)
//
// Register-sliding-window version: no LDS, no barrier. Each thread produces
// VEC=8 consecutive complex outputs from a 20-float2 register window loaded
// as 10 aligned float4. Inter-thread window overlap is deduped by L1/L2, so
// HBM traffic stays ~1.0x ideal (read 256 MiB + write 256 MiB).

constexpr int N_SAMP = 262144;
constexpr int BATCH  = 128;
constexpr int TAPS   = 11;
constexpr int BLOCK  = 256;
constexpr int VEC    = 8;               // complex outputs per thread
constexpr int TILE   = BLOCK * VEC;     // 2048 complex per block
constexpr int NW     = VEC + 12;        // 20-float2 window: [c-6, c+14)

__global__ __launch_bounds__(BLOCK)
void fir_complex_kernel(const float2* __restrict__ X,
                        const float*  __restrict__ phi,
                        float2*       __restrict__ out)
{
    const int  t    = threadIdx.x;
    const int  b    = blockIdx.y;
    const long long row = (long long)b * N_SAMP;
    const int  c    = blockIdx.x * TILE + t * VEC;  // first output index
    const int  w0   = c - 6;                        // window start (even -> float4-aligned)

    // Taps at uniform addresses -> scalar loads, live in SGPRs.
    float pr[TAPS], pi[TAPS];
#pragma unroll
    for (int k = 0; k < TAPS; ++k) {
        pr[k] = phi[2 * k + 0];
        pi[k] = phi[2 * k + 1];
    }

    // Load the input window into registers.
    float2 w[NW];
    const bool interior = (w0 >= 0) && (w0 + NW <= N_SAMP);
    if (interior) {
        const float4* p = (const float4*)(X + row + w0);
#pragma unroll
        for (int i = 0; i < NW / 2; ++i) {
            const float4 v = p[i];
            w[2 * i + 0] = make_float2(v.x, v.y);
            w[2 * i + 1] = make_float2(v.z, v.w);
        }
    } else {
#pragma unroll
        for (int i = 0; i < NW; ++i) {
            const int n = w0 + i;
            w[i] = ((unsigned)n < (unsigned)N_SAMP) ? X[row + n]
                                                    : make_float2(0.0f, 0.0f);
        }
    }

    // Sliding-window complex FIR, all operands in registers.
    float2 acc[VEC];
#pragma unroll
    for (int j = 0; j < VEC; ++j) {
        float re = 0.0f, im = 0.0f;
#pragma unroll
        for (int k = 0; k < TAPS; ++k) {
            // input index n = c + j - 5 + k  ->  window slot j + k + 1
            const float2 v = w[j + k + 1];
            re = fmaf(v.x,  pr[k], re);
            re = fmaf(-v.y, pi[k], re);
            im = fmaf(v.x,  pi[k], im);
            im = fmaf(v.y,  pr[k], im);
        }
        acc[j] = make_float2(re, im);
    }

    // Coalesced-enough stores: 4 float4 per thread, lane stride 64 B;
    // the 4 complementary dwordx4 ops cover contiguous cachelines.
    float4* po = (float4*)(out + row + c);
#pragma unroll
    for (int i = 0; i < VEC / 2; ++i) {
        po[i] = make_float4(acc[2 * i].x, acc[2 * i].y,
                            acc[2 * i + 1].x, acc[2 * i + 1].y);
    }
}

extern "C" void kernel_launch(void* const* d_in, const int* in_sizes, int n_in,
                              void* d_out, int out_size, void* d_ws, size_t ws_size,
                              hipStream_t stream)
{
    const float2* X   = (const float2*)d_in[0];
    const float*  phi = (const float*)d_in[1];
    float2*       out = (float2*)d_out;

    dim3 grid(N_SAMP / TILE, BATCH);   // 128 x 128 = 16384 blocks
    fir_complex_kernel<<<grid, BLOCK, 0, stream>>>(X, phi, out);
}